// Round 1
// baseline (1188.690 us; speedup 1.0000x reference)
//
#include <hip/hip_runtime.h>
#include <hip/hip_bf16.h>
#include <stdint.h>

// Problem constants
#define M_ROWS 32768
#define N_CODES 8192
#define K_DIM 256
#define AK (2*K_DIM)   // A storage: [zh | zl*2^6] per row (512 f16)
#define BK3 (3*K_DIM)  // B storage: [eh | el*2^11 | eh*2^-6] per row (768 f16)

// GEMM tile config (m97 structure)
#define BM 128
#define BN 128
#define BKT 32
#define GN 8           // N-blocks per swizzle panel (L2 locality)

typedef _Float16 half8 __attribute__((ext_vector_type(8)));
typedef float f32x4 __attribute__((ext_vector_type(4)));
typedef __attribute__((address_space(3))) void lds_void;
typedef const __attribute__((address_space(1))) void gbl_cvoid;

// Monotone map: fp32 bits -> uint32 preserving < order (handles sign)
__device__ __forceinline__ unsigned long long pack_key(float d, unsigned col) {
    unsigned u = __float_as_uint(d);
    u = (u & 0x80000000u) ? ~u : (u | 0x80000000u);
    return ((unsigned long long)u << 32) | (unsigned long long)col;
}

// ---------------- prep: split fp32 -> f16 hi/lo, plus squared norms ----------
__global__ __launch_bounds__(256) void prep_a(const float* __restrict__ z,
                                              _Float16* __restrict__ Aq,
                                              float* __restrict__ zsq) {
    int row = blockIdx.x, t = threadIdx.x;
    float v = z[(size_t)row * K_DIM + t];
    _Float16 hi = (_Float16)v;
    float hif = (float)hi;
    Aq[(size_t)row * AK + t]          = hi;
    Aq[(size_t)row * AK + K_DIM + t]  = (_Float16)((v - hif) * 64.0f);   // zl*2^6
    float sq = v * v;
    #pragma unroll
    for (int m = 32; m; m >>= 1) sq += __shfl_xor(sq, m);
    __shared__ float part[4];
    if ((t & 63) == 0) part[t >> 6] = sq;
    __syncthreads();
    if (t == 0) zsq[row] = (part[0] + part[1]) + (part[2] + part[3]);
}

__global__ __launch_bounds__(256) void prep_b(const float* __restrict__ cb,
                                              _Float16* __restrict__ Bq,
                                              float* __restrict__ esq) {
    int row = blockIdx.x, t = threadIdx.x;
    float v = cb[(size_t)row * K_DIM + t];
    _Float16 hi = (_Float16)v;
    float hif = (float)hi;
    Bq[(size_t)row * BK3 + t]            = hi;
    Bq[(size_t)row * BK3 + K_DIM + t]    = (_Float16)((v - hif) * 2048.0f); // el*2^11
    Bq[(size_t)row * BK3 + 2*K_DIM + t]  = (_Float16)(hif * (1.0f/64.0f)); // eh*2^-6
    float sq = v * v;
    #pragma unroll
    for (int m = 32; m; m >>= 1) sq += __shfl_xor(sq, m);
    __shared__ float part[4];
    if ((t & 63) == 0) part[t >> 6] = sq;
    __syncthreads();
    if (t == 0) esq[row] = (part[0] + part[1]) + (part[2] + part[3]);
}

// ---------------- main GEMM + fused argmin ----------------------------------
// cross = zh*eh + zh*el + zl*eh  (accurate to ~2^-23 rel)
// Phase 0 (kt 0..7):  A chunk0 (zh)      x B chunk1 (el*2^11) -> acc (scaled 2^11)
//   then acc *= 2^-11
// Phase 1 (kt 0..7):  A chunk0 (zh)      x B chunk0 (eh)
// Phase 2 (kt 0..7):  A chunk1 (zl*2^6)  x B chunk2 (eh*2^-6)
__global__ __launch_bounds__(256) void gemm_argmin(
        const _Float16* __restrict__ Aq, const _Float16* __restrict__ Bq,
        const float* __restrict__ zsq, const float* __restrict__ esq,
        unsigned long long* __restrict__ best) {
    __shared__ __align__(16) _Float16 As[BM * BKT];  // 8 KB
    __shared__ __align__(16) _Float16 Bs[BN * BKT];  // 8 KB

    int bid = blockIdx.x;
    int bm = (bid / GN) % (M_ROWS / BM);
    int bn = (bid / (GN * (M_ROWS / BM))) * GN + (bid % GN);
    int m0 = bm * BM, n0 = bn * BN;

    int t = threadIdx.x;
    int lane = t & 63, wave = t >> 6;
    int quad = lane >> 4, l15 = lane & 15;
    int wm = (wave & 1) * 64, wn = (wave >> 1) * 64;

    f32x4 acc[4][4] = {};

    const _Float16* Ag = Aq + (size_t)m0 * AK;
    const _Float16* Bg = Bq + (size_t)n0 * BK3;

    // stage 128 rows x 32 f16 from gbase(+row*stride) into lds, lane-contiguous
    auto stage = [&](const _Float16* gbase, int stride, _Float16* lds) {
        #pragma unroll
        for (int i = 0; i < 2; ++i) {
            int c = t + i * 256;               // chunk id 0..511
            int row = c >> 2, seg = c & 3;     // 4x16B chunks per 64B row
            const _Float16* gp = gbase + (size_t)row * stride + seg * 8;
            __builtin_amdgcn_global_load_lds((gbl_cvoid*)gp,
                                             (lds_void*)(lds + (size_t)c * 8),
                                             16, 0, 0);
        }
    };

    auto compute = [&]() {
        half8 af[4], bf[4];
        #pragma unroll
        for (int i = 0; i < 4; ++i) {
            af[i] = *(const half8*)&As[(wm + i * 16 + l15) * BKT + quad * 8];
            bf[i] = *(const half8*)&Bs[(wn + i * 16 + l15) * BKT + quad * 8];
        }
        #pragma unroll
        for (int mi = 0; mi < 4; ++mi)
            #pragma unroll
            for (int ni = 0; ni < 4; ++ni)
                acc[mi][ni] = __builtin_amdgcn_mfma_f32_16x16x32_f16(
                    af[mi], bf[ni], acc[mi][ni], 0, 0, 0);
    };

    #pragma unroll 1
    for (int ph = 0; ph < 3; ++ph) {
        int ao = (ph == 2) ? K_DIM : 0;
        int bo = (ph == 0) ? K_DIM : ((ph == 1) ? 0 : 2 * K_DIM);
        #pragma unroll 1
        for (int kt = 0; kt < 8; ++kt) {
            __syncthreads();                       // protect prior reads
            stage(Ag + ao + kt * BKT, AK, As);
            stage(Bg + bo + kt * BKT, BK3, Bs);
            __syncthreads();                       // drains vmcnt before barrier
            compute();
        }
        if (ph == 0) {
            #pragma unroll
            for (int mi = 0; mi < 4; ++mi)
                #pragma unroll
                for (int ni = 0; ni < 4; ++ni)
                    #pragma unroll
                    for (int r = 0; r < 4; ++r)
                        acc[mi][ni][r] *= (1.0f / 2048.0f);
        }
    }

    // Epilogue: d2 = (zsq - 2*cross) + esq  (exact ref op order), fused argmin.
    #pragma unroll
    for (int mi = 0; mi < 4; ++mi) {
        #pragma unroll
        for (int r = 0; r < 4; ++r) {
            int gRow = m0 + wm + mi * 16 + quad * 4 + r;
            float zs = zsq[gRow];
            unsigned long long bv = ~0ULL;
            #pragma unroll
            for (int ni = 0; ni < 4; ++ni) {
                unsigned gCol = (unsigned)(n0 + wn + ni * 16 + l15);
                float cross = acc[mi][ni][r];
                float d2 = (zs - 2.0f * cross) + esq[gCol];
                unsigned long long p = pack_key(d2, gCol);
                bv = (p < bv) ? p : bv;
            }
            #pragma unroll
            for (int m = 1; m < 16; m <<= 1) {
                unsigned long long o =
                    (unsigned long long)__shfl_xor((long long)bv, m);
                bv = (o < bv) ? o : bv;
            }
            if (l15 == 0) atomicMin(&best[gRow], bv);
        }
    }
}

// ---------------- ws-light fallback (only if ws too small) ------------------
__global__ __launch_bounds__(256) void vq_bruteforce(const float* __restrict__ z,
                                                     const float* __restrict__ cb,
                                                     float* __restrict__ out_idx) {
    __shared__ float As[128 * 16];
    __shared__ float Bs[128 * 16];
    int t = threadIdx.x;
    int tx = t & 15, ty = t >> 4;
    int r0 = blockIdx.x * 128;
    unsigned long long best[8];
    #pragma unroll
    for (int j = 0; j < 8; ++j) best[j] = ~0ULL;

    for (int n0 = 0; n0 < N_CODES; n0 += 128) {
        float acc[8][8] = {};
        for (int k0 = 0; k0 < K_DIM; k0 += 16) {
            __syncthreads();
            int row = t >> 1, c8 = (t & 1) * 8;
            #pragma unroll
            for (int j = 0; j < 8; ++j)
                As[row * 16 + c8 + j] = z[(size_t)(r0 + row) * K_DIM + k0 + c8 + j];
            #pragma unroll
            for (int j = 0; j < 8; ++j)
                Bs[row * 16 + c8 + j] = cb[(size_t)(n0 + row) * K_DIM + k0 + c8 + j];
            __syncthreads();
            #pragma unroll
            for (int k = 0; k < 16; ++k) {
                float a[8], b[8];
                #pragma unroll
                for (int j = 0; j < 8; ++j) a[j] = As[(ty * 8 + j) * 16 + k];
                #pragma unroll
                for (int j = 0; j < 8; ++j) b[j] = Bs[(tx * 8 + j) * 16 + k];
                #pragma unroll
                for (int i = 0; i < 8; ++i)
                    #pragma unroll
                    for (int j = 0; j < 8; ++j) {
                        float d = a[i] - b[j];
                        acc[i][j] += d * d;
                    }
            }
        }
        #pragma unroll
        for (int i = 0; i < 8; ++i) {
            unsigned long long bv = ~0ULL;
            #pragma unroll
            for (int j = 0; j < 8; ++j) {
                unsigned long long p =
                    pack_key(acc[i][j], (unsigned)(n0 + tx * 8 + j));
                bv = (p < bv) ? p : bv;
            }
            #pragma unroll
            for (int m = 1; m < 16; m <<= 1) {
                unsigned long long o =
                    (unsigned long long)__shfl_xor((long long)bv, m);
                bv = (o < bv) ? o : bv;
            }
            if (tx == 0 && bv < best[i]) best[i] = bv;
        }
    }
    if (tx == 0) {
        #pragma unroll
        for (int i = 0; i < 8; ++i)
            out_idx[r0 + ty * 8 + i] =
                (float)(unsigned)(best[i] & 0xFFFFFFFFULL);
    }
}

// ---------------- finalize: gather, straight-through out, loss sum ----------
__global__ __launch_bounds__(256) void finalize(const float* __restrict__ z,
                                                const float* __restrict__ cb,
                                                const unsigned long long* best,
                                                const float* idx_src,
                                                float* __restrict__ out,
                                                double* __restrict__ accum,
                                                int use_packed) {
    int row = blockIdx.x, t = threadIdx.x;
    int idx = use_packed ? (int)(unsigned)(best[row] & 0xFFFFFFFFULL)
                         : (int)idx_src[row];
    float zv = z[(size_t)row * K_DIM + t];
    float qv = cb[(size_t)idx * K_DIM + t];
    float diff = qv - zv;                      // ref: z_q - z_e
    out[(size_t)row * K_DIM + t] = zv + diff;  // ref: z_e + (z_q - z_e)
    if (t == 0) out[(size_t)M_ROWS * K_DIM + row] = (float)idx;
    float se = diff * diff;
    #pragma unroll
    for (int m = 32; m; m >>= 1) se += __shfl_xor(se, m);
    __shared__ float part[4];
    if ((t & 63) == 0) part[t >> 6] = se;
    __syncthreads();
    if (t == 0)
        atomicAdd(accum, (double)((part[0] + part[1]) + (part[2] + part[3])));
}

__global__ void write_loss(const double* __restrict__ accum,
                           float* __restrict__ out) {
    // vq_loss = codebook_loss + 0.25*commitment_loss = 1.25 * mean(diff^2)
    out[(size_t)M_ROWS * K_DIM + M_ROWS] =
        (float)(1.25 * (*accum / (double)((size_t)M_ROWS * K_DIM)));
}

// ---------------- launch ----------------------------------------------------
extern "C" void kernel_launch(void* const* d_in, const int* in_sizes, int n_in,
                              void* d_out, int out_size, void* d_ws, size_t ws_size,
                              hipStream_t stream) {
    const float* z  = (const float*)d_in[0];
    const float* cb = (const float*)d_in[1];
    float* out = (float*)d_out;
    float* out_idx = out + (size_t)M_ROWS * K_DIM;

    size_t szA = (size_t)M_ROWS * AK * sizeof(_Float16);   // 32 MB
    size_t szB = (size_t)N_CODES * BK3 * sizeof(_Float16); // 12 MB
    size_t offB   = szA;
    size_t offZ   = offB + szB;
    size_t offE   = offZ + (size_t)M_ROWS * sizeof(float);
    size_t offP   = offE + (size_t)N_CODES * sizeof(float);
    size_t offAcc = offP + (size_t)M_ROWS * sizeof(unsigned long long);
    size_t need   = offAcc + 16;

    if (ws_size >= need) {
        _Float16* Aq = (_Float16*)((char*)d_ws);
        _Float16* Bq = (_Float16*)((char*)d_ws + offB);
        float* zsq   = (float*)((char*)d_ws + offZ);
        float* esq   = (float*)((char*)d_ws + offE);
        unsigned long long* packed = (unsigned long long*)((char*)d_ws + offP);
        double* accum = (double*)((char*)d_ws + offAcc);

        hipMemsetAsync((char*)d_ws + offP, 0xFF,
                       (size_t)M_ROWS * sizeof(unsigned long long), stream);
        hipMemsetAsync((char*)d_ws + offAcc, 0, sizeof(double), stream);

        prep_a<<<M_ROWS, 256, 0, stream>>>(z, Aq, zsq);
        prep_b<<<N_CODES, 256, 0, stream>>>(cb, Bq, esq);
        gemm_argmin<<<(M_ROWS / BM) * (N_CODES / BN), 256, 0, stream>>>(
            Aq, Bq, zsq, esq, packed);
        finalize<<<M_ROWS, 256, 0, stream>>>(z, cb, packed, nullptr, out, accum, 1);
        write_loss<<<1, 1, 0, stream>>>(accum, out);
    } else {
        double* accum = (double*)d_ws;
        hipMemsetAsync(d_ws, 0, sizeof(double), stream);
        vq_bruteforce<<<M_ROWS / 128, 256, 0, stream>>>(z, cb, out_idx);
        finalize<<<M_ROWS, 256, 0, stream>>>(z, cb, nullptr, out_idx, out, accum, 0);
        write_loss<<<1, 1, 0, stream>>>(accum, out);
    }
}

// Round 2
// 731.816 us; speedup vs baseline: 1.6243x; 1.6243x over previous
//
#include <hip/hip_runtime.h>
#include <hip/hip_bf16.h>
#include <stdint.h>

// Problem constants
#define M_ROWS 32768
#define N_CODES 8192
#define K_DIM 256
#define AK (2*K_DIM)   // A storage: [zh | zl*2^6] per row (512 f16)
#define BK3 (3*K_DIM)  // B storage: [eh*2^6 | el*2^6 | eh] per row (768 f16)
// Single K=768 pass: chunk products zh*(eh*2^6), zh*(el*2^6), (zl*2^6)*eh
// all carry scale 2^6 -> cross = acc * 2^-6; key = esq - 2*cross = esq - acc*2^-5.

// GEMM tile config (m97 structure)
#define BM 128
#define BN 128
#define BKT 32
#define GN 8           // N-blocks per swizzle panel (L2 locality)

typedef _Float16 half8 __attribute__((ext_vector_type(8)));
typedef _Float16 h4v __attribute__((ext_vector_type(4)));
typedef float f4v __attribute__((ext_vector_type(4)));
typedef float f32x4 __attribute__((ext_vector_type(4)));
typedef __attribute__((address_space(3))) void lds_void;
typedef const __attribute__((address_space(1))) void gbl_cvoid;

// Monotone map: fp32 bits -> uint32 preserving < order (handles sign)
__device__ __forceinline__ unsigned long long pack_key(float d, unsigned col) {
    unsigned u = __float_as_uint(d);
    u = (u & 0x80000000u) ? ~u : (u | 0x80000000u);
    return ((unsigned long long)u << 32) | (unsigned long long)col;
}

// ---------------- prep A: pure elementwise split (grid-stride, float4) ------
__global__ __launch_bounds__(256) void prep_a(const float* __restrict__ z,
                                              _Float16* __restrict__ Aq) {
    int tid = blockIdx.x * 256 + threadIdx.x;
    const f4v* z4 = (const f4v*)z;
    #pragma unroll 1
    for (int i = tid; i < M_ROWS * (K_DIM / 4); i += 1024 * 256) {
        f4v v = z4[i];
        int row = i >> 6, c4 = i & 63;
        h4v hi, lo;
        #pragma unroll
        for (int j = 0; j < 4; ++j) {
            _Float16 h = (_Float16)v[j];
            hi[j] = h;
            lo[j] = (_Float16)((v[j] - (float)h) * 64.0f);
        }
        *(h4v*)&Aq[(size_t)row * AK + c4 * 4]         = hi;
        *(h4v*)&Aq[(size_t)row * AK + K_DIM + c4 * 4] = lo;
    }
}

// ---------------- prep B: wave-per-row split + esq reduction ----------------
__global__ __launch_bounds__(256) void prep_b(const float* __restrict__ cb,
                                              _Float16* __restrict__ Bq,
                                              float* __restrict__ esq) {
    int wave = threadIdx.x >> 6, lane = threadIdx.x & 63;
    int row = blockIdx.x * 4 + wave;                 // grid = 2048 blocks
    f4v v = *(const f4v*)(cb + (size_t)row * K_DIM + lane * 4);
    h4v h6, l6, h0;
    float sq = 0.f;
    #pragma unroll
    for (int j = 0; j < 4; ++j) {
        float x = v[j];
        _Float16 h = (_Float16)x;
        float hf = (float)h;
        h6[j] = (_Float16)(hf * 64.0f);              // eh*2^6 (exact scale)
        l6[j] = (_Float16)((x - hf) * 64.0f);        // el*2^6
        h0[j] = h;                                   // eh
        sq += x * x;
    }
    _Float16* bp = Bq + (size_t)row * BK3;
    *(h4v*)&bp[lane * 4]             = h6;
    *(h4v*)&bp[K_DIM + lane * 4]     = l6;
    *(h4v*)&bp[2 * K_DIM + lane * 4] = h0;
    #pragma unroll
    for (int m = 32; m; m >>= 1) sq += __shfl_xor(sq, m);
    if (lane == 0) esq[row] = sq;
}

// ---------------- main GEMM + fused argmin ----------------------------------
__global__ __launch_bounds__(256) void gemm_argmin(
        const _Float16* __restrict__ Aq, const _Float16* __restrict__ Bq,
        const float* __restrict__ esq,
        unsigned long long* __restrict__ best) {
    __shared__ __align__(16) _Float16 As[BM * BKT];  // 8 KB
    __shared__ __align__(16) _Float16 Bs[BN * BKT];  // 8 KB

    int bid = blockIdx.x;
    int bm = (bid / GN) % (M_ROWS / BM);
    int bn = (bid / (GN * (M_ROWS / BM))) * GN + (bid % GN);
    int m0 = bm * BM, n0 = bn * BN;

    int t = threadIdx.x;
    int lane = t & 63, wave = t >> 6;
    int quad = lane >> 4, l15 = lane & 15;
    int swz = (l15 >> 2) & 3;                        // bank-conflict xor swizzle
    int wm = (wave & 1) * 64, wn = (wave >> 1) * 64;

    f32x4 acc[4][4] = {};

    const _Float16* Ag = Aq + (size_t)m0 * AK;
    const _Float16* Bg = Bq + (size_t)n0 * BK3;

    // stage 128 rows x 32 f16; LDS slot (row, s) holds global seg s ^ ((row>>2)&3)
    auto stage = [&](const _Float16* gbase, int stride, _Float16* lds) {
        #pragma unroll
        for (int i = 0; i < 2; ++i) {
            int c = t + i * 256;                     // chunk id 0..511
            int row = c >> 2, seg_s = c & 3;
            int seg_g = seg_s ^ ((row >> 2) & 3);
            const _Float16* gp = gbase + (size_t)row * stride + seg_g * 8;
            __builtin_amdgcn_global_load_lds((gbl_cvoid*)gp,
                                             (lds_void*)(lds + (size_t)c * 8),
                                             16, 0, 0);
        }
    };

    auto compute = [&]() {
        half8 af[4], bf[4];
        #pragma unroll
        for (int i = 0; i < 4; ++i) {
            af[i] = *(const half8*)&As[(wm + i * 16 + l15) * BKT + (quad ^ swz) * 8];
            bf[i] = *(const half8*)&Bs[(wn + i * 16 + l15) * BKT + (quad ^ swz) * 8];
        }
        #pragma unroll
        for (int mi = 0; mi < 4; ++mi)
            #pragma unroll
            for (int ni = 0; ni < 4; ++ni)
                acc[mi][ni] = __builtin_amdgcn_mfma_f32_16x16x32_f16(
                    af[mi], bf[ni], acc[mi][ni], 0, 0, 0);
    };

    // Single uniform K pass: 24 k-tiles. A sweeps [zh]x2 then [zl*2^6].
    #pragma unroll 1
    for (int kt = 0; kt < 24; ++kt) {
        int ao = (kt >> 4) * 256 + (kt & 7) * 32;
        int bo = kt * 32;
        __syncthreads();                             // protect prior reads
        stage(Ag + ao, AK, As);
        stage(Bg + bo, BK3, Bs);
        __syncthreads();                             // drains vmcnt before barrier
        compute();
    }

    // Epilogue: key = esq - 2*cross = esq - acc*2^-5 (zsq dropped: row-constant)
    float es[4];
    #pragma unroll
    for (int ni = 0; ni < 4; ++ni)
        es[ni] = esq[n0 + wn + ni * 16 + l15];

    #pragma unroll
    for (int mi = 0; mi < 4; ++mi) {
        #pragma unroll
        for (int r = 0; r < 4; ++r) {
            int gRow = m0 + wm + mi * 16 + quad * 4 + r;
            unsigned long long bv = ~0ULL;
            #pragma unroll
            for (int ni = 0; ni < 4; ++ni) {
                unsigned gCol = (unsigned)(n0 + wn + ni * 16 + l15);
                float key = fmaf(-0.03125f, acc[mi][ni][r], es[ni]);
                unsigned long long p = pack_key(key, gCol);
                bv = (p < bv) ? p : bv;
            }
            #pragma unroll
            for (int m = 1; m < 16; m <<= 1) {
                unsigned long long o =
                    (unsigned long long)__shfl_xor((long long)bv, m);
                bv = (o < bv) ? o : bv;
            }
            if (l15 == 0) atomicMin(&best[gRow], bv);
        }
    }
}

// ---------------- ws-light fallback (only if ws too small) ------------------
__global__ __launch_bounds__(256) void vq_bruteforce(const float* __restrict__ z,
                                                     const float* __restrict__ cb,
                                                     float* __restrict__ out_idx) {
    __shared__ float As[128 * 16];
    __shared__ float Bs[128 * 16];
    int t = threadIdx.x;
    int tx = t & 15, ty = t >> 4;
    int r0 = blockIdx.x * 128;
    unsigned long long best[8];
    #pragma unroll
    for (int j = 0; j < 8; ++j) best[j] = ~0ULL;

    for (int n0 = 0; n0 < N_CODES; n0 += 128) {
        float acc[8][8] = {};
        for (int k0 = 0; k0 < K_DIM; k0 += 16) {
            __syncthreads();
            int row = t >> 1, c8 = (t & 1) * 8;
            #pragma unroll
            for (int j = 0; j < 8; ++j)
                As[row * 16 + c8 + j] = z[(size_t)(r0 + row) * K_DIM + k0 + c8 + j];
            #pragma unroll
            for (int j = 0; j < 8; ++j)
                Bs[row * 16 + c8 + j] = cb[(size_t)(n0 + row) * K_DIM + k0 + c8 + j];
            __syncthreads();
            #pragma unroll
            for (int k = 0; k < 16; ++k) {
                float a[8], b[8];
                #pragma unroll
                for (int j = 0; j < 8; ++j) a[j] = As[(ty * 8 + j) * 16 + k];
                #pragma unroll
                for (int j = 0; j < 8; ++j) b[j] = Bs[(tx * 8 + j) * 16 + k];
                #pragma unroll
                for (int i = 0; i < 8; ++i)
                    #pragma unroll
                    for (int j = 0; j < 8; ++j) {
                        float d = a[i] - b[j];
                        acc[i][j] += d * d;
                    }
            }
        }
        #pragma unroll
        for (int i = 0; i < 8; ++i) {
            unsigned long long bv = ~0ULL;
            #pragma unroll
            for (int j = 0; j < 8; ++j) {
                unsigned long long p =
                    pack_key(acc[i][j], (unsigned)(n0 + tx * 8 + j));
                bv = (p < bv) ? p : bv;
            }
            #pragma unroll
            for (int m = 1; m < 16; m <<= 1) {
                unsigned long long o =
                    (unsigned long long)__shfl_xor((long long)bv, m);
                bv = (o < bv) ? o : bv;
            }
            if (tx == 0 && bv < best[i]) best[i] = bv;
        }
    }
    if (tx == 0) {
        #pragma unroll
        for (int i = 0; i < 8; ++i)
            out_idx[r0 + ty * 8 + i] =
                (float)(unsigned)(best[i] & 0xFFFFFFFFULL);
    }
}

// ---------------- finalize: gather, straight-through out, loss sum ----------
// wave-per-row, grid-stride; one double atomic per block.
__global__ __launch_bounds__(256) void finalize(const float* __restrict__ z,
                                                const float* __restrict__ cb,
                                                const unsigned long long* __restrict__ best,
                                                float* __restrict__ out,
                                                double* __restrict__ accum,
                                                int use_packed) {
    int wave = threadIdx.x >> 6, lane = threadIdx.x & 63;
    float* out_idx = out + (size_t)M_ROWS * K_DIM;
    float se = 0.f;
    #pragma unroll 1
    for (int row = blockIdx.x * 4 + wave; row < M_ROWS; row += 1024 * 4) {
        int idx = use_packed ? (int)(unsigned)(best[row] & 0xFFFFFFFFULL)
                             : (int)out_idx[row];
        f4v zv = *(const f4v*)(z  + (size_t)row * K_DIM + lane * 4);
        f4v qv = *(const f4v*)(cb + (size_t)idx * K_DIM + lane * 4);
        f4v ov;
        #pragma unroll
        for (int j = 0; j < 4; ++j) {
            float d = qv[j] - zv[j];                 // ref: z_q - z_e
            ov[j] = zv[j] + d;                       // ref: z_e + (z_q - z_e)
            se += d * d;
        }
        *(f4v*)(out + (size_t)row * K_DIM + lane * 4) = ov;
        if (lane == 0) out_idx[row] = (float)idx;
    }
    #pragma unroll
    for (int m = 32; m; m >>= 1) se += __shfl_xor(se, m);
    __shared__ float part[4];
    if (lane == 0) part[wave] = se;
    __syncthreads();
    if (threadIdx.x == 0)
        atomicAdd(accum, (double)((part[0] + part[1]) + (part[2] + part[3])));
}

__global__ void write_loss(const double* __restrict__ accum,
                           float* __restrict__ out) {
    // vq_loss = codebook_loss + 0.25*commitment_loss = 1.25 * mean(diff^2)
    out[(size_t)M_ROWS * K_DIM + M_ROWS] =
        (float)(1.25 * (*accum / (double)((size_t)M_ROWS * K_DIM)));
}

// ---------------- launch ----------------------------------------------------
extern "C" void kernel_launch(void* const* d_in, const int* in_sizes, int n_in,
                              void* d_out, int out_size, void* d_ws, size_t ws_size,
                              hipStream_t stream) {
    const float* z  = (const float*)d_in[0];
    const float* cb = (const float*)d_in[1];
    float* out = (float*)d_out;
    float* out_idx = out + (size_t)M_ROWS * K_DIM;

    size_t szA = (size_t)M_ROWS * AK * sizeof(_Float16);   // 32 MB
    size_t szB = (size_t)N_CODES * BK3 * sizeof(_Float16); // 12 MB
    size_t offB   = szA;
    size_t offE   = offB + szB;
    size_t offP   = offE + (size_t)N_CODES * sizeof(float);
    size_t offAcc = offP + (size_t)M_ROWS * sizeof(unsigned long long);
    size_t need   = offAcc + 16;

    if (ws_size >= need) {
        _Float16* Aq = (_Float16*)((char*)d_ws);
        _Float16* Bq = (_Float16*)((char*)d_ws + offB);
        float* esq   = (float*)((char*)d_ws + offE);
        unsigned long long* packed = (unsigned long long*)((char*)d_ws + offP);
        double* accum = (double*)((char*)d_ws + offAcc);

        hipMemsetAsync((char*)d_ws + offP, 0xFF,
                       (size_t)M_ROWS * sizeof(unsigned long long), stream);
        hipMemsetAsync((char*)d_ws + offAcc, 0, sizeof(double), stream);

        prep_a<<<1024, 256, 0, stream>>>(z, Aq);
        prep_b<<<N_CODES / 4, 256, 0, stream>>>(cb, Bq, esq);
        gemm_argmin<<<(M_ROWS / BM) * (N_CODES / BN), 256, 0, stream>>>(
            Aq, Bq, esq, packed);
        finalize<<<1024, 256, 0, stream>>>(z, cb, packed, out, accum, 1);
        write_loss<<<1, 1, 0, stream>>>(accum, out);
    } else {
        double* accum = (double*)d_ws;
        hipMemsetAsync(d_ws, 0, sizeof(double), stream);
        vq_bruteforce<<<M_ROWS / 128, 256, 0, stream>>>(z, cb, out_idx);
        finalize<<<1024, 256, 0, stream>>>(z, cb, nullptr, out, accum, 0);
        write_loss<<<1, 1, 0, stream>>>(accum, out);
    }
}